// Round 5
// baseline (245.842 us; speedup 1.0000x reference)
//
#include <hip/hip_runtime.h>
#include <hip/hip_bf16.h>

// ---------------------------------------------------------------------------
// Sizes (fixed)
// ---------------------------------------------------------------------------
#define BATCH 4
#define NN    256
#define DD    600
#define HH    256
#define MROWS (BATCH*NN)   // 1024
#define KPAD  640          // DD padded to multiple of 64
#define NBLK  256          // persistent grid: 1 block per CU

typedef __attribute__((ext_vector_type(8))) short bf16x8;   // 8 bf16 (4 VGPRs)
typedef __attribute__((ext_vector_type(4))) float f32x4;

__device__ __forceinline__ void gload16(const void* g, void* l)
{
    __builtin_amdgcn_global_load_lds(
        (const __attribute__((address_space(1))) void*)g,
        (__attribute__((address_space(3))) void*)l, 16, 0, 0);
}

// ---------------------------------------------------------------------------
// Software grid barrier (persistent kernel, monotonic counter, no reset).
// Counter zeroed by hipMemsetAsync before launch. Device-scope atomics +
// agent fences (wbl2/inv on gfx950) give cross-XCD visibility.
// ---------------------------------------------------------------------------
__device__ __forceinline__ void gbar(unsigned* bar, unsigned tgt)
{
    __syncthreads();
    if (threadIdx.x == 0) {
        __threadfence();   // release: drain + L2 writeback
        __hip_atomic_fetch_add(bar, 1u, __ATOMIC_RELAXED, __HIP_MEMORY_SCOPE_AGENT);
        while (__hip_atomic_load(bar, __ATOMIC_RELAXED, __HIP_MEMORY_SCOPE_AGENT) < tgt)
            __builtin_amdgcn_s_sleep(2);
        __threadfence();   // acquire: L1/L2 invalidate
    }
    __syncthreads();
}

// ---------------------------------------------------------------------------
// bf16 MFMA GEMM tile (device): C = A[M,K] @ BT^T (+bias cols<biasN) (+relu)
// Tile 64x64x64, 256 threads = 4 waves (2x2), 32x32/wave.
// WF32: fp32 C (cols<Nvalid). WB16: bf16 C (all cols).
// WHT: also write hT[b][d][j] via LDS retile (M must be 1024 = 4b x 256j).
// ---------------------------------------------------------------------------
template<bool BIAS, bool RELU, bool WF32, bool WB16, bool WHT>
__device__ void gemm_tile(
    char* lds, int row0, int col0, int bz,
    const __hip_bfloat16* __restrict__ A, const __hip_bfloat16* __restrict__ BT,
    const float* __restrict__ bias,
    float* __restrict__ Cf, __hip_bfloat16* __restrict__ Cb,
    __hip_bfloat16* __restrict__ hT,
    int K, int lda, int ldb, int ldcf, int ldcb, int Nvalid, int biasN,
    long long sA, long long sBT, long long sCf, long long sCb)
{
    char* ldsA = lds;
    char* ldsB = lds + 8192;

    const int tid  = threadIdx.x;
    const int lane = tid & 63;
    const int wid  = tid >> 6;
    const int wr   = wid >> 1;
    const int wc   = wid & 1;

    const char* Ab = (const char*)A + (bz * sA + (long long)row0 * lda) * 2;
    const char* Bb = (const char*)BT + (bz * sBT + (long long)col0 * ldb) * 2;

    const int sr   = tid >> 3;                    // 0..31
    const int scb  = (tid & 7) * 16;              // 0..112
    const int scbs = scb ^ ((sr & 7) << 4);       // inverse source swizzle

    const char* gA0 = Ab + (long long)sr        * (lda * 2) + scbs;
    const char* gA1 = Ab + (long long)(sr + 32) * (lda * 2) + scbs;
    const char* gB0 = Bb + (long long)sr        * (ldb * 2) + scbs;
    const char* gB1 = Bb + (long long)(sr + 32) * (ldb * 2) + scbs;

    char* dA0 = ldsA + wid * 1024;
    char* dA1 = ldsA + 4096 + wid * 1024;
    char* dB0 = ldsB + wid * 1024;
    char* dB1 = ldsB + 4096 + wid * 1024;

    f32x4 acc[2][2] = {};

    const int fr = lane & 15;
    const int kg = (lane >> 4) * 16;
    const int xv = (fr & 7) << 4;       // read-side XOR swizzle

    const int nk = K >> 6;
    for (int t = 0; t < nk; ++t) {
        gload16(gA0, dA0); gload16(gA1, dA1);
        gload16(gB0, dB0); gload16(gB1, dB1);
        gA0 += 128; gA1 += 128; gB0 += 128; gB1 += 128;
        __syncthreads();
        #pragma unroll
        for (int ks = 0; ks < 2; ++ks) {
            const int kb = ks * 64 + kg;
            bf16x8 a0 = *(const bf16x8*)(ldsA + (wr * 32 + fr)      * 128 + (kb ^ xv));
            bf16x8 a1 = *(const bf16x8*)(ldsA + (wr * 32 + 16 + fr) * 128 + (kb ^ xv));
            bf16x8 b0 = *(const bf16x8*)(ldsB + (wc * 32 + fr)      * 128 + (kb ^ xv));
            bf16x8 b1 = *(const bf16x8*)(ldsB + (wc * 32 + 16 + fr) * 128 + (kb ^ xv));
            acc[0][0] = __builtin_amdgcn_mfma_f32_16x16x32_bf16(a0, b0, acc[0][0], 0, 0, 0);
            acc[0][1] = __builtin_amdgcn_mfma_f32_16x16x32_bf16(a0, b1, acc[0][1], 0, 0, 0);
            acc[1][0] = __builtin_amdgcn_mfma_f32_16x16x32_bf16(a1, b0, acc[1][0], 0, 0, 0);
            acc[1][1] = __builtin_amdgcn_mfma_f32_16x16x32_bf16(a1, b1, acc[1][1], 0, 0, 0);
        }
        __syncthreads();
    }

    // epilogue: C/D frag mapping col=lane&15, row=(lane>>4)*4+reg
    const int er = (lane >> 4) * 4;
    const int ec = lane & 15;
    __hip_bfloat16* sT = (__hip_bfloat16*)lds;   // [64][72] retile buffer

    #pragma unroll
    for (int mi = 0; mi < 2; ++mi) {
        #pragma unroll
        for (int ni = 0; ni < 2; ++ni) {
            const int lr0 = wr * 32 + mi * 16 + er;
            const int lc  = wc * 32 + ni * 16 + ec;
            const int gr = row0 + lr0;
            const int gc = col0 + lc;
            const float bv = (BIAS && gc < biasN) ? bias[gc] : 0.f;
            #pragma unroll
            for (int r = 0; r < 4; ++r) {
                float v = acc[mi][ni][r] + bv;
                if (RELU) v = fmaxf(v, 0.f);
                const __hip_bfloat16 hv = __float2bfloat16(v);
                const long long row = gr + r;
                if (WF32 && gc < Nvalid)
                    Cf[bz * sCf + row * ldcf + gc] = v;
                if (WB16)
                    Cb[bz * sCb + row * ldcb + gc] = hv;
                if (WHT)
                    sT[(lr0 + r) * 72 + lc] = hv;
            }
        }
    }

    if (WHT) {
        __syncthreads();
        const int b  = row0 >> 8;
        const int i0 = row0 & 255;
        const int cc = tid >> 3;         // 0..31
        const int ch = tid & 7;          // j-chunk of 8
        #pragma unroll
        for (int p = 0; p < 2; ++p) {
            const int d = col0 + cc + p * 32;
            __align__(16) __hip_bfloat16 tmp[8];
            #pragma unroll
            for (int u = 0; u < 8; ++u)
                tmp[u] = sT[(ch * 8 + u) * 72 + cc + p * 32];
            *(float4*)&hT[((long long)b * KPAD + d) * NN + i0 + ch * 8] = *(float4*)tmp;
        }
        __syncthreads();   // LDS free before next use
    }
}

// ---------------------------------------------------------------------------
// Prep stage: xb = bf16(pad(feature)); W0T/W1T/aW1T via 32x32 LDS transpose.
// 1760 units striped over NBLK blocks.
// ---------------------------------------------------------------------------
__device__ void prep_stage(
    char* smem, int bid,
    const float* __restrict__ feature, const float* __restrict__ W0,
    const float* __restrict__ W1, const float* __restrict__ aW1,
    __hip_bfloat16* __restrict__ xb, __hip_bfloat16* __restrict__ W0T,
    __hip_bfloat16* __restrict__ W1T, __hip_bfloat16* __restrict__ aW1T)
{
    const int tid = threadIdx.x;
    float (*tile)[33] = (float(*)[33])smem;
    for (int u = bid; u < 1760; u += NBLK) {
        if (u < 640) {
            const int idx = (u * 256 + tid) * 4;
            const int r = idx / KPAD, c = idx % KPAD;
            float4 v = make_float4(0.f, 0.f, 0.f, 0.f);
            if (c < DD) v = *(const float4*)&feature[r * DD + c];   // DD%4==0
            __align__(8) __hip_bfloat16 o[4] = {
                __float2bfloat16(v.x), __float2bfloat16(v.y),
                __float2bfloat16(v.z), __float2bfloat16(v.w)};
            *(float2*)&xb[idx] = *(float2*)o;
        } else {
            const int t = u - 640;
            const int which = (t < 400) ? 0 : (t < 800) ? 1 : 2;
            const int tt = (which == 0) ? t : (which == 1) ? t - 400 : t - 800;
            const int n0 = (tt / 20) * 32;
            const int k0 = (tt % 20) * 32;
            const int tx = tid & 31, ty = tid >> 5;
            __syncthreads();   // protect LDS reuse across loop iterations
            #pragma unroll
            for (int r = 0; r < 4; ++r) {
                const int k = k0 + ty + r * 8;
                const int n = n0 + tx;
                float v = 0.f;
                if (which == 0)      { if (k < DD && n < DD) v = W0[k * DD + n]; }
                else if (which == 1) { if (k < DD && n < DD) v = W1[k * DD + n]; }
                else                 { if (k < DD) v = (n < HH) ? aW1[k * HH + n]
                                                                : aW1[(DD + k) * HH + (n - HH)]; }
                tile[ty + r * 8][tx] = v;
            }
            __syncthreads();
            __hip_bfloat16* dst = (which == 0) ? W0T : (which == 1) ? W1T : aW1T;
            #pragma unroll
            for (int r = 0; r < 4; ++r) {
                const int n = n0 + ty + r * 8;
                const int k = k0 + tx;
                dst[n * KPAD + k] = __float2bfloat16(tile[tx][ty + r * 8]);
            }
        }
    }
    __syncthreads();
}

// ---------------------------------------------------------------------------
// Attention stage: score + leaky_relu + mask + softmax + *adj -> att (bf16)
// unit = blockIdx.x: b = unit>>6, rows i0 = (unit&63)*4.
// ---------------------------------------------------------------------------
__device__ __forceinline__ void block_max4(float* v, float (*red)[4])
{
    #pragma unroll
    for (int o = 32; o > 0; o >>= 1)
        #pragma unroll
        for (int q = 0; q < 4; ++q) v[q] = fmaxf(v[q], __shfl_down(v[q], o));
    const int lane = threadIdx.x & 63, w = threadIdx.x >> 6;
    if (lane == 0) { red[w][0]=v[0]; red[w][1]=v[1]; red[w][2]=v[2]; red[w][3]=v[3]; }
    __syncthreads();
    #pragma unroll
    for (int q = 0; q < 4; ++q)
        v[q] = fmaxf(fmaxf(red[0][q], red[1][q]), fmaxf(red[2][q], red[3][q]));
    __syncthreads();
}

__device__ __forceinline__ void block_sum4(float* v, float (*red)[4])
{
    #pragma unroll
    for (int o = 32; o > 0; o >>= 1)
        #pragma unroll
        for (int q = 0; q < 4; ++q) v[q] += __shfl_down(v[q], o);
    const int lane = threadIdx.x & 63, w = threadIdx.x >> 6;
    if (lane == 0) { red[w][0]=v[0]; red[w][1]=v[1]; red[w][2]=v[2]; red[w][3]=v[3]; }
    __syncthreads();
    #pragma unroll
    for (int q = 0; q < 4; ++q)
        v[q] = red[0][q] + red[1][q] + red[2][q] + red[3][q];
    __syncthreads();
}

__device__ void attn_stage(
    char* smem, int bid,
    const float* __restrict__ LR, const float* __restrict__ aW2,
    const float* __restrict__ ab2, const float* __restrict__ adj,
    __hip_bfloat16* __restrict__ att)
{
    float (*sL)[HH] = (float(*)[HH])smem;            // 4 KB
    float* sW       = (float*)(smem + 4096);         // 1 KB
    float (*red)[4] = (float(*)[4])(smem + 5120);    // 64 B

    const int b  = bid >> 6;
    const int i0 = (bid & 63) * 4;
    const int j  = threadIdx.x;

    sW[j] = aW2[j];
    #pragma unroll
    for (int q = 0; q < 4; ++q)
        sL[q][j] = LR[((long long)(b * NN + i0 + q)) * 512 + j];
    __syncthreads();

    const float* rp = LR + ((long long)(b * NN + j)) * 512 + HH;
    float acc[4] = {0.f, 0.f, 0.f, 0.f};
    for (int h = 0; h < HH; h += 8) {
        const float4 ra = *(const float4*)(rp + h);
        const float4 rb = *(const float4*)(rp + h + 4);
        const float4 w0 = *(const float4*)&sW[h];
        const float4 w1 = *(const float4*)&sW[h + 4];
        #pragma unroll
        for (int q = 0; q < 4; ++q) {
            const float4 l0 = *(const float4*)&sL[q][h];
            const float4 l1 = *(const float4*)&sL[q][h + 4];
            float s = fmaxf(l0.x + ra.x, 0.f) * w0.x;
            s += fmaxf(l0.y + ra.y, 0.f) * w0.y;
            s += fmaxf(l0.z + ra.z, 0.f) * w0.z;
            s += fmaxf(l0.w + ra.w, 0.f) * w0.w;
            s += fmaxf(l1.x + rb.x, 0.f) * w1.x;
            s += fmaxf(l1.y + rb.y, 0.f) * w1.y;
            s += fmaxf(l1.z + rb.z, 0.f) * w1.z;
            s += fmaxf(l1.w + rb.w, 0.f) * w1.w;
            acc[q] += s;
        }
    }

    const float ab2v = ab2[0];
    float m[4], a[4];
    #pragma unroll
    for (int q = 0; q < 4; ++q) {
        float e = acc[q] + ab2v;
        e = (e > 0.f) ? e : 0.01f * e;                       // leaky_relu
        a[q] = adj[((long long)(b * NN + i0 + q)) * NN + j];
        m[q] = (a[q] == 0.f) ? -1e9f : e;                    // mask
    }
    float mx[4] = {m[0], m[1], m[2], m[3]};
    block_max4(mx, red);
    float p[4];
    #pragma unroll
    for (int q = 0; q < 4; ++q) p[q] = __expf(m[q] - mx[q]);
    float s[4] = {p[0], p[1], p[2], p[3]};
    block_sum4(s, red);
    #pragma unroll
    for (int q = 0; q < 4; ++q)
        att[((long long)(b * NN + i0 + q)) * NN + j] = __float2bfloat16(p[q] / s[q] * a[q]);
    __syncthreads();
}

// ---------------------------------------------------------------------------
// Persistent mega-kernel: all 9 stages, 8 internal grid barriers.
// ---------------------------------------------------------------------------
__global__ __launch_bounds__(256) void gat_mega(
    const float* __restrict__ feature, const float* __restrict__ adj,
    const float* __restrict__ W0, const float* __restrict__ b0,
    const float* __restrict__ W1, const float* __restrict__ b1,
    const float* __restrict__ aW1, const float* __restrict__ ab1,
    const float* __restrict__ aW2, const float* __restrict__ ab2,
    __hip_bfloat16* __restrict__ xb, __hip_bfloat16* __restrict__ W0T,
    __hip_bfloat16* __restrict__ W1T, __hip_bfloat16* __restrict__ aW1T,
    __hip_bfloat16* __restrict__ hb, __hip_bfloat16* __restrict__ hT,
    __hip_bfloat16* __restrict__ att, float* __restrict__ LR,
    float* __restrict__ out, unsigned* __restrict__ bar)
{
    __shared__ __align__(16) char smem[16640];
    const int bid = blockIdx.x;
    unsigned tgt = 0;

    prep_stage(smem, bid, feature, W0, W1, aW1, xb, W0T, W1T, aW1T);
    tgt += NBLK; gbar(bar, tgt);

    #pragma unroll 1
    for (int layer = 0; layer < 2; ++layer) {
        const __hip_bfloat16* WT = layer ? W1T : W0T;
        const float* bb          = layer ? b1 : b0;

        // hb = xb @ W + b  [1024][640] bf16, + hT[b][d][j]
        if (bid < 160)
            gemm_tile<true, false, false, true, true>(smem, (bid / 10) * 64, (bid % 10) * 64, 0,
                xb, WT, bb, nullptr, hb, hT,
                KPAD, KPAD, KPAD, 0, KPAD, 0, DD, 0, 0, 0, 0);
        tgt += NBLK; gbar(bar, tgt);

        // LR = hb @ aW1T^T (+ab1 on cols<256)  [1024][512] fp32
        if (bid < 128)
            gemm_tile<true, false, true, false, false>(smem, (bid / 8) * 64, (bid % 8) * 64, 0,
                hb, aW1T, ab1, LR, nullptr, nullptr,
                KPAD, KPAD, KPAD, 512, 0, 512, HH, 0, 0, 0, 0);
        tgt += NBLK; gbar(bar, tgt);

        // att = softmax(mask(leaky(score))) * adj  bf16
        attn_stage(smem, bid, LR, aW2, ab2, adj, att);
        tgt += NBLK; gbar(bar, tgt);

        // out = relu(att @ h): layer0 -> xb (bf16, next input); layer1 -> out fp32
        if (bid < 160) {
            const int bz = bid / 40, rem = bid % 40;
            const int row0 = (rem / 10) * 64, col0 = (rem % 10) * 64;
            if (layer == 0)
                gemm_tile<false, true, false, true, false>(smem, row0, col0, bz,
                    att, hT, nullptr, nullptr, xb, nullptr,
                    NN, NN, NN, 0, KPAD, 0, 0,
                    (long long)NN * NN, (long long)KPAD * NN, 0, (long long)NN * KPAD);
            else
                gemm_tile<false, true, true, false, false>(smem, row0, col0, bz,
                    att, hT, nullptr, out, nullptr, nullptr,
                    NN, NN, NN, DD, 0, DD, 0,
                    (long long)NN * NN, (long long)KPAD * NN, (long long)NN * DD, 0);
        }
        if (layer == 0) { tgt += NBLK; gbar(bar, tgt); }
    }
}

// ---------------------------------------------------------------------------
// Launch: memset barrier counter + one persistent kernel.
// ---------------------------------------------------------------------------
extern "C" void kernel_launch(void* const* d_in, const int* in_sizes, int n_in,
                              void* d_out, int out_size, void* d_ws, size_t ws_size,
                              hipStream_t stream)
{
    const float* feature = (const float*)d_in[0];
    const float* adj     = (const float*)d_in[1];
    const float* W0      = (const float*)d_in[2];
    const float* b0      = (const float*)d_in[3];
    const float* W1      = (const float*)d_in[4];
    const float* b1      = (const float*)d_in[5];
    const float* aW1     = (const float*)d_in[6];
    const float* ab1     = (const float*)d_in[7];
    const float* aW2     = (const float*)d_in[8];
    const float* ab2     = (const float*)d_in[9];
    float* out = (float*)d_out;

    __hip_bfloat16* bw = (__hip_bfloat16*)d_ws;
    __hip_bfloat16* xb   = bw;                       // 1024*640
    __hip_bfloat16* W0T  = xb   + MROWS * KPAD;      // 640*640
    __hip_bfloat16* W1T  = W0T  + KPAD * KPAD;       // 640*640
    __hip_bfloat16* aW1T = W1T  + KPAD * KPAD;       // 512*640
    __hip_bfloat16* hb   = aW1T + 512 * KPAD;        // 1024*640
    __hip_bfloat16* hT   = hb   + MROWS * KPAD;      // 4*640*256
    __hip_bfloat16* att  = hT   + BATCH * KPAD * NN; // 4*256*256
    float* LR = (float*)(att + BATCH * NN * NN);     // 1024*512 fp32
    unsigned* bar = (unsigned*)((char*)d_ws + (32u << 20));  // isolated line

    hipMemsetAsync(bar, 0, 64, stream);
    gat_mega<<<NBLK, 256, 0, stream>>>(
        feature, adj, W0, b0, W1, b1, aW1, ab1, aW2, ab2,
        xb, W0T, W1T, aW1T, hb, hT, att, LR, out, bar);
}

// Round 6
// 68.508 us; speedup vs baseline: 3.5885x; 3.5885x over previous
//
#include <hip/hip_runtime.h>
#include <hip/hip_bf16.h>

// ---------------------------------------------------------------------------
// Sizes (fixed)
// ---------------------------------------------------------------------------
#define BATCH 4
#define NN    256
#define DD    600
#define HH    256
#define MROWS (BATCH*NN)   // 1024
#define KPAD  640          // DD padded to multiple of 64

typedef __attribute__((ext_vector_type(8))) short bf16x8;   // 8 bf16 (4 VGPRs)
typedef __attribute__((ext_vector_type(4))) float f32x4;

__device__ __forceinline__ void gload16(const void* g, void* l)
{
    __builtin_amdgcn_global_load_lds(
        (const __attribute__((address_space(1))) void*)g,
        (__attribute__((address_space(3))) void*)l, 16, 0, 0);
}

// counted vmcnt wait; n is compile-time after full unroll -> folds to one inst
__device__ __forceinline__ void waitcnt_vm(int n)
{
    switch (n) {
    case 0:  asm volatile("s_waitcnt vmcnt(0)"  ::: "memory"); break;
    case 4:  asm volatile("s_waitcnt vmcnt(4)"  ::: "memory"); break;
    case 8:  asm volatile("s_waitcnt vmcnt(8)"  ::: "memory"); break;
    case 12: asm volatile("s_waitcnt vmcnt(12)" ::: "memory"); break;
    default: asm volatile("s_waitcnt vmcnt(0)"  ::: "memory"); break;
    }
}

// ---------------------------------------------------------------------------
// bf16 MFMA GEMM: C = A[M,K] @ BT^T (+bias cols<biasN) (+relu), K = NK*64.
// Tile 64x64x64, 256 threads = 4 waves (2x2), 32x32/wave.
// Ring-4 LDS buffers (64 KB): loads for tile t+3 in flight during compute of
// tile t; counted vmcnt + raw s_barrier per K-step (T3/T4 pattern).
// WF32: fp32 C (cols<Nvalid). WB16: bf16 C (all cols).
// WHT: also write hT[b][d][j] via LDS retile (M must be 1024 = 4b x 256j).
// LDS XOR-swizzle (T2/m201): linear global_load_lds dest + inverse-swizzled
// global source + swizzled ds_read_b128.
// ---------------------------------------------------------------------------
template<bool BIAS, bool RELU, bool WF32, bool WB16, bool WHT, int NK>
__global__ __launch_bounds__(256) void gemm_mfma(
    const __hip_bfloat16* __restrict__ A, const __hip_bfloat16* __restrict__ BT,
    const float* __restrict__ bias,
    float* __restrict__ Cf, __hip_bfloat16* __restrict__ Cb,
    __hip_bfloat16* __restrict__ hT,
    int lda, int ldb, int ldcf, int ldcb, int Nvalid, int biasN,
    long long sA, long long sBT, long long sCf, long long sCb)
{
    __shared__ __align__(16) char lds[65536];   // ring: tile t -> A at (t&3)*8K, B at 32K+(t&3)*8K

    const int bz   = blockIdx.z;
    const int tid  = threadIdx.x;
    const int lane = tid & 63;
    const int wid  = tid >> 6;
    const int wr   = wid >> 1;
    const int wc   = wid & 1;
    const int row0 = blockIdx.y * 64;
    const int col0 = blockIdx.x * 64;

    const char* Ab = (const char*)A + (bz * sA + (long long)row0 * lda) * 2;
    const char* Bb = (const char*)BT + (bz * sBT + (long long)col0 * ldb) * 2;

    const int sr   = tid >> 3;                    // 0..31
    const int scb  = (tid & 7) * 16;              // 0..112
    const int scbs = scb ^ ((sr & 7) << 4);       // inverse source swizzle

    const char* gA0 = Ab + (long long)sr        * (lda * 2) + scbs;
    const char* gA1 = Ab + (long long)(sr + 32) * (lda * 2) + scbs;
    const char* gB0 = Bb + (long long)sr        * (ldb * 2) + scbs;
    const char* gB1 = Bb + (long long)(sr + 32) * (ldb * 2) + scbs;

    f32x4 acc[2][2] = {};

    const int fr = lane & 15;
    const int kg = (lane >> 4) * 16;
    const int xv = (fr & 7) << 4;       // read-side XOR swizzle

    auto issue = [&](int t) {
        char* bA = lds + (t & 3) * 8192;
        char* bB = lds + 32768 + (t & 3) * 8192;
        const long long off = (long long)t * 128;
        gload16(gA0 + off, bA + wid * 1024);
        gload16(gA1 + off, bA + 4096 + wid * 1024);
        gload16(gB0 + off, bB + wid * 1024);
        gload16(gB1 + off, bB + 4096 + wid * 1024);
    };

    constexpr int PRE = (NK < 3) ? NK : 3;
    #pragma unroll
    for (int p = 0; p < PRE; ++p) issue(p);

    #pragma unroll
    for (int t = 0; t < NK; ++t) {
        const int imax = (t + 2 < NK - 1) ? t + 2 : NK - 1;   // last issued tile
        waitcnt_vm(4 * (imax - t));          // tile t's 4 loads complete (per wave)
        __builtin_amdgcn_s_barrier();        // all waves' loads for tile t landed
        const char* ldsA = lds + (t & 3) * 8192;
        const char* ldsB = lds + 32768 + (t & 3) * 8192;
        #pragma unroll
        for (int ks = 0; ks < 2; ++ks) {
            const int kb = ks * 64 + kg;
            bf16x8 a0 = *(const bf16x8*)(ldsA + (wr * 32 + fr)      * 128 + (kb ^ xv));
            bf16x8 a1 = *(const bf16x8*)(ldsA + (wr * 32 + 16 + fr) * 128 + (kb ^ xv));
            bf16x8 b0 = *(const bf16x8*)(ldsB + (wc * 32 + fr)      * 128 + (kb ^ xv));
            bf16x8 b1 = *(const bf16x8*)(ldsB + (wc * 32 + 16 + fr) * 128 + (kb ^ xv));
            acc[0][0] = __builtin_amdgcn_mfma_f32_16x16x32_bf16(a0, b0, acc[0][0], 0, 0, 0);
            acc[0][1] = __builtin_amdgcn_mfma_f32_16x16x32_bf16(a0, b1, acc[0][1], 0, 0, 0);
            acc[1][0] = __builtin_amdgcn_mfma_f32_16x16x32_bf16(a1, b0, acc[1][0], 0, 0, 0);
            acc[1][1] = __builtin_amdgcn_mfma_f32_16x16x32_bf16(a1, b1, acc[1][1], 0, 0, 0);
        }
        if (t + 3 < NK) issue(t + 3);        // into buffer (t-1)&3: reads done pre-barrier
    }
    __syncthreads();                          // all LDS reads done (sT reuse below)

    // epilogue: C/D frag mapping col=lane&15, row=(lane>>4)*4+reg
    const int er = (lane >> 4) * 4;
    const int ec = lane & 15;
    __hip_bfloat16* sT = (__hip_bfloat16*)lds;   // [64][72] retile buffer

    #pragma unroll
    for (int mi = 0; mi < 2; ++mi) {
        #pragma unroll
        for (int ni = 0; ni < 2; ++ni) {
            const int lr0 = wr * 32 + mi * 16 + er;
            const int lc  = wc * 32 + ni * 16 + ec;
            const int gr = row0 + lr0;
            const int gc = col0 + lc;
            const float bv = (BIAS && gc < biasN) ? bias[gc] : 0.f;
            #pragma unroll
            for (int r = 0; r < 4; ++r) {
                float v = acc[mi][ni][r] + bv;
                if (RELU) v = fmaxf(v, 0.f);
                const __hip_bfloat16 hv = __float2bfloat16(v);
                const long long row = gr + r;
                if (WF32 && gc < Nvalid)
                    Cf[bz * sCf + row * ldcf + gc] = v;
                if (WB16)
                    Cb[bz * sCb + row * ldcb + gc] = hv;
                if (WHT)
                    sT[(lr0 + r) * 72 + lc] = hv;
            }
        }
    }

    if (WHT) {
        __syncthreads();
        const int b  = row0 >> 8;
        const int i0 = row0 & 255;
        const int cc = tid >> 3;         // 0..31
        const int ch = tid & 7;          // j-chunk of 8
        #pragma unroll
        for (int p = 0; p < 2; ++p) {
            const int d = col0 + cc + p * 32;
            __align__(16) __hip_bfloat16 tmp[8];
            #pragma unroll
            for (int u = 0; u < 8; ++u)
                tmp[u] = sT[(ch * 8 + u) * 72 + cc + p * 32];
            *(float4*)&hT[((long long)b * KPAD + d) * NN + i0 + ch * 8] = *(float4*)tmp;
        }
    }
}

// ---------------------------------------------------------------------------
// Prep: xb = bf16(pad(feature)) vectorized; W0T/W1T/aW1T via 32x32 LDS
// tile transpose (coalesced both sides) + bf16 convert.
// ---------------------------------------------------------------------------
__global__ __launch_bounds__(256) void prep_kernel(
    const float* __restrict__ feature, const float* __restrict__ W0,
    const float* __restrict__ W1, const float* __restrict__ aW1,
    __hip_bfloat16* __restrict__ xb, __hip_bfloat16* __restrict__ W0T,
    __hip_bfloat16* __restrict__ W1T, __hip_bfloat16* __restrict__ aW1T)
{
    const int bid = blockIdx.x;
    const int tid = threadIdx.x;
    if (bid < 640) {
        const int idx = (bid * 256 + tid) * 4;
        const int r = idx / KPAD, c = idx % KPAD;
        float4 v = make_float4(0.f, 0.f, 0.f, 0.f);
        if (c < DD) v = *(const float4*)&feature[r * DD + c];   // DD%4==0
        __align__(8) __hip_bfloat16 o[4] = {
            __float2bfloat16(v.x), __float2bfloat16(v.y),
            __float2bfloat16(v.z), __float2bfloat16(v.w)};
        *(float2*)&xb[idx] = *(float2*)o;
        return;
    }
    __shared__ float tile[32][33];
    const int t = bid - 640;
    const int which = (t < 400) ? 0 : (t < 800) ? 1 : 2;
    const int tt = (which == 0) ? t : (which == 1) ? t - 400 : t - 800;
    const int n0 = (tt / 20) * 32;
    const int k0 = (tt % 20) * 32;
    const int tx = tid & 31, ty = tid >> 5;
    #pragma unroll
    for (int r = 0; r < 4; ++r) {
        const int k = k0 + ty + r * 8;
        const int n = n0 + tx;
        float v = 0.f;
        if (which == 0)      { if (k < DD && n < DD) v = W0[k * DD + n]; }
        else if (which == 1) { if (k < DD && n < DD) v = W1[k * DD + n]; }
        else                 { if (k < DD) v = (n < HH) ? aW1[k * HH + n]
                                                        : aW1[(DD + k) * HH + (n - HH)]; }
        tile[ty + r * 8][tx] = v;
    }
    __syncthreads();
    __hip_bfloat16* dst = (which == 0) ? W0T : (which == 1) ? W1T : aW1T;
    #pragma unroll
    for (int r = 0; r < 4; ++r) {
        const int n = n0 + ty + r * 8;
        const int k = k0 + tx;
        dst[n * KPAD + k] = __float2bfloat16(tile[tx][ty + r * 8]);
    }
}

// ---------------------------------------------------------------------------
// Attention: score + leaky_relu + mask + softmax + *adj -> att (bf16)
// Block = (b, 4 rows); thread j. 256 blocks (1/CU).
// ---------------------------------------------------------------------------
__device__ __forceinline__ void block_max4(float* v, float (*red)[4])
{
    #pragma unroll
    for (int o = 32; o > 0; o >>= 1)
        #pragma unroll
        for (int q = 0; q < 4; ++q) v[q] = fmaxf(v[q], __shfl_down(v[q], o));
    const int lane = threadIdx.x & 63, w = threadIdx.x >> 6;
    if (lane == 0) { red[w][0]=v[0]; red[w][1]=v[1]; red[w][2]=v[2]; red[w][3]=v[3]; }
    __syncthreads();
    #pragma unroll
    for (int q = 0; q < 4; ++q)
        v[q] = fmaxf(fmaxf(red[0][q], red[1][q]), fmaxf(red[2][q], red[3][q]));
    __syncthreads();
}

__device__ __forceinline__ void block_sum4(float* v, float (*red)[4])
{
    #pragma unroll
    for (int o = 32; o > 0; o >>= 1)
        #pragma unroll
        for (int q = 0; q < 4; ++q) v[q] += __shfl_down(v[q], o);
    const int lane = threadIdx.x & 63, w = threadIdx.x >> 6;
    if (lane == 0) { red[w][0]=v[0]; red[w][1]=v[1]; red[w][2]=v[2]; red[w][3]=v[3]; }
    __syncthreads();
    #pragma unroll
    for (int q = 0; q < 4; ++q)
        v[q] = red[0][q] + red[1][q] + red[2][q] + red[3][q];
    __syncthreads();
}

__global__ __launch_bounds__(256) void attn_kernel(
    const float* __restrict__ LR, const float* __restrict__ aW2,
    const float* __restrict__ ab2, const float* __restrict__ adj,
    __hip_bfloat16* __restrict__ att)
{
    __shared__ float sL[4][HH];
    __shared__ float sW[HH];
    __shared__ float red[4][4];

    const int b  = blockIdx.y;
    const int i0 = blockIdx.x * 4;
    const int j  = threadIdx.x;

    sW[j] = aW2[j];
    #pragma unroll
    for (int q = 0; q < 4; ++q)
        sL[q][j] = LR[((long long)(b * NN + i0 + q)) * 512 + j];
    __syncthreads();

    const float* rp = LR + ((long long)(b * NN + j)) * 512 + HH;
    float acc[4] = {0.f, 0.f, 0.f, 0.f};
    for (int h = 0; h < HH; h += 8) {
        const float4 ra = *(const float4*)(rp + h);
        const float4 rb = *(const float4*)(rp + h + 4);
        const float4 w0 = *(const float4*)&sW[h];
        const float4 w1 = *(const float4*)&sW[h + 4];
        #pragma unroll
        for (int q = 0; q < 4; ++q) {
            const float4 l0 = *(const float4*)&sL[q][h];
            const float4 l1 = *(const float4*)&sL[q][h + 4];
            float s = fmaxf(l0.x + ra.x, 0.f) * w0.x;
            s += fmaxf(l0.y + ra.y, 0.f) * w0.y;
            s += fmaxf(l0.z + ra.z, 0.f) * w0.z;
            s += fmaxf(l0.w + ra.w, 0.f) * w0.w;
            s += fmaxf(l1.x + rb.x, 0.f) * w1.x;
            s += fmaxf(l1.y + rb.y, 0.f) * w1.y;
            s += fmaxf(l1.z + rb.z, 0.f) * w1.z;
            s += fmaxf(l1.w + rb.w, 0.f) * w1.w;
            acc[q] += s;
        }
    }

    const float ab2v = ab2[0];
    float m[4], a[4];
    #pragma unroll
    for (int q = 0; q < 4; ++q) {
        float e = acc[q] + ab2v;
        e = (e > 0.f) ? e : 0.01f * e;                       // leaky_relu
        a[q] = adj[((long long)(b * NN + i0 + q)) * NN + j];
        m[q] = (a[q] == 0.f) ? -1e9f : e;                    // mask
    }
    float mx[4] = {m[0], m[1], m[2], m[3]};
    block_max4(mx, red);
    float p[4];
    #pragma unroll
    for (int q = 0; q < 4; ++q) p[q] = __expf(m[q] - mx[q]);
    float s[4] = {p[0], p[1], p[2], p[3]};
    block_sum4(s, red);
    #pragma unroll
    for (int q = 0; q < 4; ++q)
        att[((long long)(b * NN + i0 + q)) * NN + j] = __float2bfloat16(p[q] / s[q] * a[q]);
}

// ---------------------------------------------------------------------------
// Launch
// ---------------------------------------------------------------------------
extern "C" void kernel_launch(void* const* d_in, const int* in_sizes, int n_in,
                              void* d_out, int out_size, void* d_ws, size_t ws_size,
                              hipStream_t stream)
{
    const float* feature = (const float*)d_in[0];
    const float* adj     = (const float*)d_in[1];
    const float* W0      = (const float*)d_in[2];
    const float* b0      = (const float*)d_in[3];
    const float* W1      = (const float*)d_in[4];
    const float* b1      = (const float*)d_in[5];
    const float* aW1     = (const float*)d_in[6];
    const float* ab1     = (const float*)d_in[7];
    const float* aW2     = (const float*)d_in[8];
    const float* ab2     = (const float*)d_in[9];
    float* out = (float*)d_out;

    __hip_bfloat16* bw = (__hip_bfloat16*)d_ws;
    __hip_bfloat16* xb   = bw;                       // 1024*640
    __hip_bfloat16* W0T  = xb   + MROWS * KPAD;      // 640*640
    __hip_bfloat16* W1T  = W0T  + KPAD * KPAD;       // 640*640
    __hip_bfloat16* aW1T = W1T  + KPAD * KPAD;       // 512*640
    __hip_bfloat16* hb   = aW1T + 512 * KPAD;        // 1024*640
    __hip_bfloat16* hT   = hb   + MROWS * KPAD;      // 4*640*256
    __hip_bfloat16* att  = hT   + BATCH * KPAD * NN; // 4*256*256
    float* LR = (float*)(att + BATCH * NN * NN);     // 1024*512 fp32

    prep_kernel<<<1760, 256, 0, stream>>>(feature, W0, W1, aW1, xb, W0T, W1T, aW1T);

    for (int layer = 0; layer < 2; ++layer) {
        const __hip_bfloat16* WT = layer ? W1T : W0T;
        const float* bb          = layer ? b1 : b0;

        // hb = x @ W + b  [1024][640] bf16 ; also hT[b][d][j]
        gemm_mfma<true, false, false, true, true, KPAD/64><<<dim3(KPAD / 64, MROWS / 64, 1), 256, 0, stream>>>(
            xb, WT, bb, nullptr, hb, hT,
            KPAD, KPAD, 0, KPAD, 0, DD, 0, 0, 0, 0);

        // LR = hb @ aW1T^T (+ab1 on cols<256)   [1024][512] fp32
        gemm_mfma<true, false, true, false, false, KPAD/64><<<dim3(512 / 64, MROWS / 64, 1), 256, 0, stream>>>(
            hb, aW1T, ab1, LR, nullptr, nullptr,
            KPAD, KPAD, 512, 0, 512, HH, 0, 0, 0, 0);

        // att = softmax(mask(leaky(score))) * adj   bf16
        attn_kernel<<<dim3(NN / 4, BATCH), 256, 0, stream>>>(LR, aW2, ab2, adj, att);

        // out = relu(att @ h): layer0 -> xb (bf16); layer1 -> out fp32
        if (layer == 0) {
            gemm_mfma<false, true, false, true, false, NN/64><<<dim3(KPAD / 64, NN / 64, BATCH), 256, 0, stream>>>(
                att, hT, nullptr, nullptr, xb, nullptr,
                NN, NN, 0, KPAD, 0, 0,
                (long long)NN * NN, (long long)KPAD * NN, 0, (long long)NN * KPAD);
        } else {
            gemm_mfma<false, true, true, false, false, NN/64><<<dim3(KPAD / 64, NN / 64, BATCH), 256, 0, stream>>>(
                att, hT, nullptr, out, nullptr, nullptr,
                NN, NN, DD, 0, DD, 0,
                (long long)NN * NN, (long long)KPAD * NN, (long long)NN * DD, 0);
        }
    }
}